// Round 1
// baseline (1335.742 us; speedup 1.0000x reference)
//
#include <hip/hip_runtime.h>
#include <math.h>

constexpr int kS  = 384;
constexpr int kS1 = 385;
constexpr int kH  = 8;
constexpr int kB  = 32;
constexpr int kD  = 256;
constexpr float kEPS = 1e-8f;
// (1/0.05) * log2(e)
constexpr float kNEG_INV_EPS_LOG2E = 28.853900817779268f;

__device__ __forceinline__ float waveReduceSum(float v) {
    #pragma unroll
    for (int m = 1; m < 64; m <<= 1) v += __shfl_xor(v, m);
    return v;
}
__device__ __forceinline__ float waveReduceMax(float v) {
    #pragma unroll
    for (int m = 1; m < 64; m <<= 1) v = fmaxf(v, __shfl_xor(v, m));
    return v;
}

// ---------------------------------------------------------------------------
// K1: per-(b,h) entropic GW -> alpha[head].  One block per head (256 blocks).
// Writes SYM (symmetrized affinity) into sym_ws (the d_out attn region, used
// as scratch; fully overwritten later by k2).
// ---------------------------------------------------------------------------
__global__ __launch_bounds__(384) void k1_gw(
    const float* __restrict__ shared_attn,   // [B,H,385,385]
    const float* __restrict__ DG,            // [B,H,16,16]
    const float* __restrict__ bmarg,         // [B,H,16]
    float* __restrict__ sym_ws,              // per-head stride 385*385, uses 384*384
    float* __restrict__ alpha_out)           // [256]
{
    const int head = blockIdx.x;
    const int tid  = threadIdx.x;            // 0..383 ; tid == row index i
    const int lane = tid & 63, wid = tid >> 6;

    __shared__ __align__(16) float uni[8320];    // 33280B: PassA tiles / Ms[384][16]
    __shared__ float Ks[kS * 17];                // 26112B K-matrix rows, pad 17
    __shared__ float ravu[kS];                   // rowsum -> a -> u
    __shared__ float part[16 * 24];
    __shared__ float C2l[256];
    __shared__ float bl16[16], cb16[16], cC216[16], vls[16];
    __shared__ float wred[6];

    float* tA = uni;                 // [64][65]
    float* tB = uni + 4160;          // [64][65]
    float* Ms = uni;                 // [384][16], float4-aligned

    const float* P = shared_attn + (size_t)head * (kS1 * kS1);
    float* SYM = sym_ws + (size_t)head * (kS1 * kS1);

    ravu[tid] = 0.f;
    if (tid < 256) C2l[tid] = DG[head * 256 + tid];
    if (tid >= 256 && tid < 272) bl16[tid - 256] = bmarg[head * 16 + (tid - 256)];
    __syncthreads();

    // ---- Pass A: symmetrize, write SYM, rowsums, max -----------------------
    float mymax = -1e30f;
    for (int ti = 0; ti < 6; ++ti)
    for (int tj = ti; tj < 6; ++tj) {
        for (int e = tid; e < 4096; e += 384) {
            int r = e >> 6, c = e & 63;
            tA[r * 65 + c] = P[(ti * 64 + r + 1) * kS1 + (tj * 64 + c + 1)];
            tB[r * 65 + c] = P[(tj * 64 + r + 1) * kS1 + (ti * 64 + c + 1)];
        }
        __syncthreads();
        for (int e = tid; e < 4096; e += 384) {
            int r = e >> 6, c = e & 63;
            float v = 0.5f * (tA[r * 65 + c] + tB[c * 65 + r]);
            tA[r * 65 + c] = v;                   // in-place: S-tile
            mymax = fmaxf(mymax, v);
        }
        __syncthreads();
        for (int e = tid; e < 4096; e += 384) {
            int r = e >> 6, c = e & 63;
            SYM[(ti * 64 + r) * kS + tj * 64 + c] = tA[r * 65 + c];
        }
        if (ti != tj) {
            for (int e = tid; e < 4096; e += 384) {
                int r = e >> 6, c = e & 63;
                SYM[(tj * 64 + r) * kS + ti * 64 + c] = tA[c * 65 + r];
            }
        }
        if (tid < 64) {
            int r = tid; float s = 0.f;
            #pragma unroll 8
            for (int c = 0; c < 64; ++c) s += tA[r * 65 + c];
            ravu[ti * 64 + r] += s;
        } else if (tid < 128 && ti != tj) {
            int c = tid - 64; float s = 0.f;
            #pragma unroll 8
            for (int r = 0; r < 64; ++r) s += tA[r * 65 + c];
            ravu[tj * 64 + c] += s;
        }
        __syncthreads();
    }

    // ---- reductions: mx, total --------------------------------------------
    float wm = waveReduceMax(mymax);
    if (lane == 0) wred[wid] = wm;
    __syncthreads();
    const float mx = fmaxf(fmaxf(fmaxf(wred[0], wred[1]), fmaxf(wred[2], wred[3])),
                           fmaxf(wred[4], wred[5]));
    float tloc = ravu[tid];
    float tw = waveReduceSum(tloc);
    __syncthreads();
    if (lane == 0) wred[wid] = tw;
    __syncthreads();
    const float total = wred[0] + wred[1] + wred[2] + wred[3] + wred[4] + wred[5];

    const float den_mx = fmaxf(mx, kEPS);
    const float inv_mx = 1.0f / den_mx;
    const float Sdeg   = total * inv_mx;
    const float den_a  = fmaxf(Sdeg, kEPS);
    const float a_reg  = (tloc * inv_mx) / den_a;
    __syncthreads();               // everyone done reading old ravu (own elems only, but be safe)
    ravu[tid] = a_reg;             // ravu now holds a[]

    if (tid < 16) {
        float cb = 0.f, cc2 = 0.f;
        #pragma unroll
        for (int k = 0; k < 16; ++k) {
            cb += bl16[k] * C2l[tid * 16 + k];          // cb[l]  = sum_k b_k C2[l,k]
            float c2 = C2l[k * 16 + tid];               // C2[k,l]
            cc2 = fmaf(bl16[k] * c2, c2, cc2);          // cC2[l] = sum_k b_k C2[k,l]^2
        }
        cb16[tid] = cb; cC216[tid] = cc2;
    }
    __syncthreads();

    // ---- outer iter 1 (closed form: T = a (x) b) --------------------------
    float t1 = 0.f, t2 = 0.f;
    {
        const float* symcol = SYM + tid;
        #pragma unroll 4
        for (int s = 0; s < kS; ++s) {
            float sym = symcol[s * kS];
            float dp  = fmaf(-inv_mx, sym, 1.0f);
            float as  = ravu[s];
            t1 = fmaf(dp, as, t1);
            t2 = fmaf(dp * dp, as, t2);
        }
    }
    const float cc1 = t2;    // cC1[i]
    #pragma unroll
    for (int l = 0; l < 16; ++l) {
        float tens = cc1 + cC216[l] - 2.0f * cb16[l] * t1;
        Ks[tid * 17 + l] = exp2f(tens * (-kNEG_INV_EPS_LOG2E));
    }

    float vreg[16];
    float u_i = 0.f;

    auto sinkhorn = [&]() {
        #pragma unroll
        for (int l = 0; l < 16; ++l) vreg[l] = 1.0f;
        for (int it = 0; it < 20; ++it) {
            float su = 0.f;
            #pragma unroll
            for (int l = 0; l < 16; ++l) su = fmaf(Ks[tid * 17 + l], vreg[l], su);
            u_i = a_reg / fmaxf(su, 1e-30f);
            ravu[tid] = u_i;                       // ravu now holds u[]
            __syncthreads();
            {
                int l = tid & 15, g = tid >> 4;
                float sv = 0.f;
                #pragma unroll
                for (int j = 0; j < 16; ++j)
                    sv = fmaf(Ks[(g * 16 + j) * 17 + l], ravu[g * 16 + j], sv);
                part[l * 24 + g] = sv;
            }
            __syncthreads();
            if (tid < 16) {
                float dn = 0.f;
                #pragma unroll
                for (int g = 0; g < 24; ++g) dn += part[tid * 24 + g];
                vls[tid] = bl16[tid] / fmaxf(dn, 1e-30f);
            }
            __syncthreads();
            #pragma unroll
            for (int l = 0; l < 16; ++l) vreg[l] = vls[l];
        }
    };

    __syncthreads();        // all Ks rows written before sinkhorn's cross-row reads
    sinkhorn();

    float tens16[16];
    #pragma unroll
    for (int l = 0; l < 16; ++l) tens16[l] = 0.f;

    for (int outer = 1; outer < 5; ++outer) {
        // ---- M-phase: Ms[s][l] = u_s * sum_k K[s,k] v_k C2[l,k] ----------
        {
            float wk[16];
            #pragma unroll
            for (int k = 0; k < 16; ++k) wk[k] = Ks[tid * 17 + k] * vreg[k];
            float m[16];
            #pragma unroll
            for (int l = 0; l < 16; ++l) {
                float acc = 0.f;
                #pragma unroll
                for (int k = 0; k < 16; ++k) acc = fmaf(wk[k], C2l[l * 16 + k], acc);
                m[l] = acc * u_i;
            }
            float4* Ms4 = (float4*)Ms;
            Ms4[tid * 4 + 0] = make_float4(m[0],  m[1],  m[2],  m[3]);
            Ms4[tid * 4 + 1] = make_float4(m[4],  m[5],  m[6],  m[7]);
            Ms4[tid * 4 + 2] = make_float4(m[8],  m[9],  m[10], m[11]);
            Ms4[tid * 4 + 3] = make_float4(m[12], m[13], m[14], m[15]);
        }
        __syncthreads();
        // ---- stream: rd[l] = sum_s DP[i,s] * Ms[s][l]   (DP symmetric) ---
        float rd[16];
        #pragma unroll
        for (int l = 0; l < 16; ++l) rd[l] = 0.f;
        {
            const float* symcol = SYM + tid;
            const float4* Ms4 = (const float4*)Ms;
            #pragma unroll 2
            for (int s = 0; s < kS; ++s) {
                float sym = symcol[s * kS];
                float dp  = fmaf(-inv_mx, sym, 1.0f);
                float4 m0 = Ms4[s * 4 + 0];
                float4 m1 = Ms4[s * 4 + 1];
                float4 m2 = Ms4[s * 4 + 2];
                float4 m3 = Ms4[s * 4 + 3];
                rd[0]  = fmaf(dp, m0.x, rd[0]);  rd[1]  = fmaf(dp, m0.y, rd[1]);
                rd[2]  = fmaf(dp, m0.z, rd[2]);  rd[3]  = fmaf(dp, m0.w, rd[3]);
                rd[4]  = fmaf(dp, m1.x, rd[4]);  rd[5]  = fmaf(dp, m1.y, rd[5]);
                rd[6]  = fmaf(dp, m1.z, rd[6]);  rd[7]  = fmaf(dp, m1.w, rd[7]);
                rd[8]  = fmaf(dp, m2.x, rd[8]);  rd[9]  = fmaf(dp, m2.y, rd[9]);
                rd[10] = fmaf(dp, m2.z, rd[10]); rd[11] = fmaf(dp, m2.w, rd[11]);
                rd[12] = fmaf(dp, m3.x, rd[12]); rd[13] = fmaf(dp, m3.y, rd[13]);
                rd[14] = fmaf(dp, m3.z, rd[14]); rd[15] = fmaf(dp, m3.w, rd[15]);
            }
        }
        #pragma unroll
        for (int l = 0; l < 16; ++l) {
            float tens = cc1 + cC216[l] - 2.0f * rd[l];
            if (outer == 4) tens16[l] = tens;
            Ks[tid * 17 + l] = exp2f(tens * (-kNEG_INV_EPS_LOG2E));
        }
        __syncthreads();    // Ms fully consumed & Ks rewritten before sinkhorn
        sinkhorn();
    }

    // ---- gw = sum tens * (u K v), alpha = exp(-gw) -------------------------
    float g = 0.f;
    #pragma unroll
    for (int l = 0; l < 16; ++l)
        g = fmaf(tens16[l] * Ks[tid * 17 + l], vreg[l], g);
    g *= u_i;
    float gww = waveReduceSum(g);
    __syncthreads();
    if (lane == 0) wred[wid] = gww;
    __syncthreads();
    if (tid == 0) {
        float gw = wred[0] + wred[1] + wred[2] + wred[3] + wred[4] + wred[5];
        alpha_out[head] = expf(-gw);
    }
}

// ---------------------------------------------------------------------------
// K2: sharpen prior_Q by alpha, build masked row-normalized attn [B,H,385,385]
// One wave per row. The two row-normalizations cancel: attn = p / (sum - pdiag)
// with ref's EPS clamps mirrored.
// ---------------------------------------------------------------------------
__global__ __launch_bounds__(256) void k2_attn(
    const float* __restrict__ priorQ,    // [B,H,384,384]
    const float* __restrict__ alpha_in,  // [256]
    float* __restrict__ attn_out)        // [B,H,385,385]
{
    const int tid  = threadIdx.x;
    const int lane = tid & 63, wid = tid >> 6;
    const int head = blockIdx.x / 97;
    const int i    = (blockIdx.x % 97) * 4 + wid;
    if (i >= kS1) return;
    float* row = attn_out + (size_t)head * (kS1 * kS1) + (size_t)i * kS1;
    if (i == 0) {
        const float val = 1.0f / 384.0f;
        for (int j = lane; j < kS1; j += 64) row[j] = (j == 0) ? 0.f : val;
        return;
    }
    const float e = 1.0f + alpha_in[head];
    const float* q = priorQ + (size_t)head * (kS * kS) + (size_t)(i - 1) * kS;
    float p[6];
    float loc = 0.f, locd = 0.f;
    #pragma unroll
    for (int k = 0; k < 6; ++k) {
        int j = lane + k * 64;
        float qv = fmaxf(q[j], kEPS);
        float pv = exp2f(e * log2f(qv));
        p[k] = pv;
        loc += pv;
        if (j == i - 1) locd = pv;
    }
    float sum = loc, pd = locd;
    #pragma unroll
    for (int m = 1; m < 64; m <<= 1) { sum += __shfl_xor(sum, m); pd += __shfl_xor(pd, m); }
    const float qsum  = fmaxf(sum, kEPS);
    const float srow  = (sum - pd) / qsum;
    const float scale = 1.0f / (qsum * fmaxf(srow, kEPS));
    if (lane == 0) row[0] = 0.f;
    #pragma unroll
    for (int k = 0; k < 6; ++k) {
        int j = lane + k * 64;
        row[1 + j] = (j == i - 1) ? 0.f : p[k] * scale;
    }
}

// ---------------------------------------------------------------------------
// K3: vfull = nv @ v_w^T + v_b   ([12320,256] @ [256,256])
// ---------------------------------------------------------------------------
__global__ __launch_bounds__(256) void k3_vproj(
    const float* __restrict__ nv,    // [B*385,256]
    const float* __restrict__ vw,    // [256,256]
    const float* __restrict__ vb,    // [256]
    float* __restrict__ vfull)       // [B*385,256]
{
    __shared__ float At[64][17];
    __shared__ float Bt[256][17];
    const int tid = threadIdx.x;
    const int r0  = blockIdx.x * 64;
    const int tx  = tid & 31;       // cols c = tx + 32*ci
    const int ty  = tid >> 5;       // rows r = r0 + ty*8 + ri
    const int M   = kB * kS1;
    float acc[8][8];
    #pragma unroll
    for (int ri = 0; ri < 8; ++ri)
        #pragma unroll
        for (int ci = 0; ci < 8; ++ci) acc[ri][ci] = 0.f;

    for (int k0 = 0; k0 < 256; k0 += 16) {
        __syncthreads();
        for (int e = tid; e < 1024; e += 256) {
            int r = e >> 4, kk = e & 15;
            int rowi = r0 + r;
            At[r][kk] = (rowi < M) ? nv[rowi * 256 + k0 + kk] : 0.f;
        }
        for (int e = tid; e < 4096; e += 256) {
            int c = e >> 4, kk = e & 15;
            Bt[c][kk] = vw[c * 256 + k0 + kk];
        }
        __syncthreads();
        #pragma unroll
        for (int kk = 0; kk < 16; ++kk) {
            float av[8], bv[8];
            #pragma unroll
            for (int ri = 0; ri < 8; ++ri) av[ri] = At[ty * 8 + ri][kk];
            #pragma unroll
            for (int ci = 0; ci < 8; ++ci) bv[ci] = Bt[tx + 32 * ci][kk];
            #pragma unroll
            for (int ri = 0; ri < 8; ++ri)
                #pragma unroll
                for (int ci = 0; ci < 8; ++ci)
                    acc[ri][ci] = fmaf(av[ri], bv[ci], acc[ri][ci]);
        }
    }
    for (int ri = 0; ri < 8; ++ri) {
        int rowi = r0 + ty * 8 + ri;
        if (rowi < M) {
            #pragma unroll
            for (int ci = 0; ci < 8; ++ci) {
                int c = tx + 32 * ci;
                vfull[rowi * 256 + c] = acc[ri][ci] + vb[c];
            }
        }
    }
}

// ---------------------------------------------------------------------------
// K4: basis[b,i,c] = sum_j attn[b, c>>5, i, j] * vfull[b,j,c]
// Block: 256 threads (c), 32 rows i, j-tiles of 24.
// ---------------------------------------------------------------------------
__global__ __launch_bounds__(256) void k4_ctx(
    const float* __restrict__ attn,    // [B,H,385,385]
    const float* __restrict__ vfull,   // [B*385,256]
    float* __restrict__ basis)         // [B,385,256]
{
    __shared__ __align__(16) float at[8 * 32 * 28];  // [h][ii][jj pad 28]
    __shared__ float vt[24 * 256];
    const int tid = threadIdx.x;
    const int bb  = blockIdx.y;
    const int i0  = blockIdx.x * 32;
    const int h   = tid >> 5;
    float acc[32];
    #pragma unroll
    for (int i = 0; i < 32; ++i) acc[i] = 0.f;
    const float* attnB = attn + (size_t)bb * kH * kS1 * kS1;
    const float* vB    = vfull + (size_t)bb * kS1 * 256;

    for (int j0 = 0; j0 < kS1; j0 += 24) {
        __syncthreads();
        for (int e = tid; e < 6144; e += 256) {
            int jj = e % 24, ii = (e / 24) & 31, hh = e / (24 * 32);
            int gi = i0 + ii, gj = j0 + jj;
            float v = (gi < kS1 && gj < kS1)
                      ? attnB[(size_t)hh * kS1 * kS1 + (size_t)gi * kS1 + gj] : 0.f;
            at[(hh * 32 + ii) * 28 + jj] = v;
        }
        for (int e = tid; e < 6144; e += 256) {
            int c = e & 255, jr = e >> 8;
            int gj = j0 + jr;
            vt[jr * 256 + c] = (gj < kS1) ? vB[gj * 256 + c] : 0.f;
        }
        __syncthreads();
        #pragma unroll
        for (int j4 = 0; j4 < 6; ++j4) {
            float v0 = vt[(j4 * 4 + 0) * 256 + tid];
            float v1 = vt[(j4 * 4 + 1) * 256 + tid];
            float v2 = vt[(j4 * 4 + 2) * 256 + tid];
            float v3 = vt[(j4 * 4 + 3) * 256 + tid];
            #pragma unroll
            for (int i = 0; i < 32; ++i) {
                float4 av = *(const float4*)&at[(h * 32 + i) * 28 + j4 * 4];
                acc[i] = fmaf(av.x, v0, fmaf(av.y, v1, fmaf(av.z, v2, fmaf(av.w, v3, acc[i]))));
            }
        }
    }
    for (int i = 0; i < 32; ++i) {
        int gi = i0 + i;
        if (gi < kS1) basis[((size_t)bb * kS1 + gi) * 256 + tid] = acc[i];
    }
}

extern "C" void kernel_launch(void* const* d_in, const int* in_sizes, int n_in,
                              void* d_out, int out_size, void* d_ws, size_t ws_size,
                              hipStream_t stream) {
    (void)in_sizes; (void)n_in; (void)out_size; (void)ws_size;
    const float* nv    = (const float*)d_in[1];
    const float* sattn = (const float*)d_in[2];
    const float* pq    = (const float*)d_in[3];
    const float* dg    = (const float*)d_in[4];
    const float* bm    = (const float*)d_in[5];
    const float* vw    = (const float*)d_in[6];
    const float* vb    = (const float*)d_in[7];

    float* out   = (float*)d_out;
    float* basis = out;                                  // 32*385*256
    float* attn  = out + (size_t)kB * kS1 * kD;          // 32*8*385*385 (also SYM scratch)
    float* alpha = (float*)d_ws;
    float* vfull = (float*)((char*)d_ws + 4096);         // 12.6 MB

    k1_gw<<<256, 384, 0, stream>>>(sattn, dg, bm, attn, alpha);
    k2_attn<<<256 * 97, 256, 0, stream>>>(pq, alpha, attn);
    k3_vproj<<<193, 256, 0, stream>>>(nv, vw, vb, vfull);
    k4_ctx<<<dim3(13, 32), 256, 0, stream>>>(attn, vfull, basis);
}